// Round 2
// baseline (679.916 us; speedup 1.0000x reference)
//
#include <hip/hip_runtime.h>
#include <hip/hip_bf16.h>

typedef _Float16 f16;
typedef _Float16 f16x8 __attribute__((ext_vector_type(8)));

#define D 128
#define N_CLS 40
#define BN 128       // nodes per bucket
#define NBMAX 1024   // padded bucket count

// Feature-sliced HS layout: 8 slices x 16 features (32B/row/slice), slice-major:
//   HS_blk[s][i][f]  (f in [0,16))  elem offset = s*(n*16) + i*16 + f
// Slice s is processed only by blocks with blockIdx.x%8==s, which land on XCD s
// (round-robin dispatch) -> per-XCD gather working set = n*32B = 3.2MB < 4MB L2.

// ---- 1. bucket histogram of dst (LDS-staged) ----
__global__ __launch_bounds__(256) void k_hist(const int* __restrict__ dst,
                                              int* __restrict__ bcnt, int e) {
  __shared__ int lh[NBMAX];
  for (int j = threadIdx.x; j < NBMAX; j += 256) lh[j] = 0;
  __syncthreads();
  int stride = gridDim.x * blockDim.x;
  for (int q = blockIdx.x * blockDim.x + threadIdx.x; q < e; q += stride)
    atomicAdd(&lh[dst[q] >> 7], 1);
  __syncthreads();
  for (int j = threadIdx.x; j < NBMAX; j += 256)
    if (lh[j]) atomicAdd(&bcnt[j], lh[j]);
}

// ---- 2. exclusive scan of bucket counts ----
__global__ __launch_bounds__(1024) void k_bscan(const int* __restrict__ bcnt,
                                                int* __restrict__ bbase,
                                                int* __restrict__ bcur) {
  __shared__ int sums[NBMAX];
  int t = threadIdx.x;
  int c = bcnt[t];
  sums[t] = c;
  __syncthreads();
  for (int off = 1; off < NBMAX; off <<= 1) {
    int a = (t >= off) ? sums[t - off] : 0;
    __syncthreads();
    sums[t] += a;
    __syncthreads();
  }
  bbase[t] = sums[t] - c;
  bcur[t] = sums[t] - c;
}

// ---- 3. bin edges into bucket-major order ----
__global__ __launch_bounds__(256) void k_place(const int* __restrict__ src,
                                               const int* __restrict__ dst,
                                               int* __restrict__ bcur,
                                               unsigned int* __restrict__ binned,
                                               int e, int nwg) {
  __shared__ int lh[NBMAX];
  __shared__ int lofs[NBMAX];
  __shared__ int lcur[NBMAX];
  int chunk = (e + nwg - 1) / nwg;
  int lo = blockIdx.x * chunk;
  int hi = min(e, lo + chunk);
  int t = threadIdx.x;
  for (int j = t; j < NBMAX; j += 256) { lh[j] = 0; lcur[j] = 0; }
  __syncthreads();
  for (int q = lo + t; q < hi; q += 256) atomicAdd(&lh[dst[q] >> 7], 1);
  __syncthreads();
  for (int j = t; j < NBMAX; j += 256) {
    int c = lh[j];
    lofs[j] = c ? atomicAdd(&bcur[j], c) : 0;
  }
  __syncthreads();
  for (int q = lo + t; q < hi; q += 256) {
    int d = dst[q];
    int b = d >> 7;
    int r = atomicAdd(&lcur[b], 1);
    binned[lofs[b] + r] = ((unsigned int)(d & 127) << 17) | (unsigned int)src[q];
  }
}

// ---- 4. per-bucket counting sort -> CSR + deg + isd + row_start ----
__global__ __launch_bounds__(256) void k_csr(const unsigned int* __restrict__ binned,
                                             const int* __restrict__ bbase,
                                             int* __restrict__ csr,
                                             int* __restrict__ deg,
                                             float* __restrict__ isd,
                                             int* __restrict__ row_start, int n) {
  int b = blockIdx.x;
  int lo = bbase[b], hi = bbase[b + 1];
  __shared__ int h[BN];
  __shared__ int sc[BN];
  __shared__ int cur[BN];
  int t = threadIdx.x;
  if (t < BN) h[t] = 0;
  __syncthreads();
  for (int q = lo + t; q < hi; q += 256) atomicAdd(&h[binned[q] >> 17], 1);
  __syncthreads();
  if (t < BN) sc[t] = h[t];
  __syncthreads();
  for (int off = 1; off < BN; off <<= 1) {
    int a = 0;
    if (t < BN && t >= off) a = sc[t - off];
    __syncthreads();
    if (t < BN) sc[t] += a;
    __syncthreads();
  }
  if (t < BN) {
    int excl = sc[t] - h[t];
    cur[t] = lo + excl;
    int i = b * BN + t;
    if (i < n) {
      deg[i] = h[t];
      isd[i] = rsqrtf((float)(h[t] + 1));
      row_start[i] = lo + excl;
    }
  }
  __syncthreads();
  for (int q = lo + t; q < hi; q += 256) {
    unsigned int u = binned[q];
    int p = atomicAdd(&cur[u >> 17], 1);
    csr[p] = (int)(u & 0x1FFFF);
  }
}

// ---- tiled GEMM: HS_blk = isd[i] * (X @ W), fp32 accum, f16 slice-major out ----
template <bool HALF_IN>
__global__ __launch_bounds__(256) void k_gemm_t(const void* __restrict__ Xv,
                                                const float* __restrict__ W,
                                                const float* __restrict__ isd,
                                                f16* __restrict__ HS, int n) {
  __shared__ float Xt[64][D + 4];
  __shared__ float Wb[32][D + 4];
  const size_t ss = (size_t)n * 16;  // slice stride in f16 elems
  int t = threadIdx.x;
  int r0 = blockIdx.x * 64;
  if (!HALF_IN) {
    const float* X = (const float*)Xv;
    for (int q = t; q < 64 * 32; q += 256) {
      int row = q >> 5, cb = (q & 31) << 2;
      float4 v = {0.f, 0.f, 0.f, 0.f};
      if (r0 + row < n) v = *(const float4*)(X + (size_t)(r0 + row) * D + cb);
      *(float4*)&Xt[row][cb] = v;
    }
  } else {
    // input is slice-major f16
    const f16* X = (const f16*)Xv;
    for (int q = t; q < 64 * 16; q += 256) {
      int row = q >> 4, cb = (q & 15) << 3;  // cb in {0,8,...,120}
      f16x8 v = 0;
      if (r0 + row < n)
        v = *(const f16x8*)(X + (size_t)(cb >> 4) * ss +
                            (size_t)(r0 + row) * 16 + (cb & 15));
      float* xp = &Xt[row][cb];
#pragma unroll
      for (int j = 0; j < 8; ++j) xp[j] = (float)v[j];
    }
  }
  int tr = ((t >> 4) & 15) << 2;
  int tc = (t & 15) << 3;
  float acc[4][8];
#pragma unroll
  for (int i = 0; i < 4; ++i)
#pragma unroll
    for (int j = 0; j < 8; ++j) acc[i][j] = 0.f;

  for (int hh = 0; hh < 4; ++hh) {
    __syncthreads();
    for (int q = t; q < 32 * 32; q += 256) {
      int row = q >> 5, cb = (q & 31) << 2;
      *(float4*)&Wb[row][cb] = *(const float4*)(W + (size_t)(hh * 32 + row) * D + cb);
    }
    __syncthreads();
#pragma unroll 4
    for (int k = 0; k < 32; ++k) {
      float4 u0 = *(const float4*)&Wb[k][tc];
      float4 u1 = *(const float4*)&Wb[k][tc + 4];
      float bv[8] = {u0.x, u0.y, u0.z, u0.w, u1.x, u1.y, u1.z, u1.w};
      int kk = hh * 32 + k;
#pragma unroll
      for (int i = 0; i < 4; ++i) {
        float a = Xt[tr + i][kk];
#pragma unroll
        for (int j = 0; j < 8; ++j) acc[i][j] += a * bv[j];
      }
    }
  }
#pragma unroll
  for (int i = 0; i < 4; ++i) {
    int row = r0 + tr + i;
    if (row < n) {
      float s = isd[row];
      f16x8 ov;
#pragma unroll
      for (int j = 0; j < 8; ++j) ov[j] = (f16)(s * acc[i][j]);
      // slice-major store
      *(f16x8*)(HS + (size_t)(tc >> 4) * ss + (size_t)row * 16 + (tc & 15)) = ov;
    }
  }
}

__device__ inline f16x8 shfl_xor_f16x8(f16x8 v, int m) {
  union { f16x8 h; int i[4]; } u;
  u.h = v;
#pragma unroll
  for (int k = 0; k < 4; ++k) u.i[k] = __shfl_xor(u.i[k], m);
  return u.h;
}

// ---- sliced aggregation: out_blk[s][i] = relu(isd[i]*(sum HS_blk[s][src] + self) + b)
// block: 256 thr = 4 waves; wave: 4 nodes (16-lane groups); group: 8 edges x 2 lanes.
// slice s = blockIdx.x & 7 (-> XCD s via round-robin dispatch).
__global__ __launch_bounds__(256) void k_aggs(const f16* __restrict__ HS,
                                              const int* __restrict__ csr,
                                              const int* __restrict__ row_start,
                                              const int* __restrict__ deg,
                                              const float* __restrict__ isd,
                                              const float* __restrict__ bias,
                                              f16* __restrict__ G, int n) {
  const size_t ss = (size_t)n * 16;
  int t = threadIdx.x;
  int wave = t >> 6, lane = t & 63;
  int g = lane >> 4, r = lane & 15;
  int s = blockIdx.x & 7;
  int i0 = ((blockIdx.x >> 3) << 4) + (wave << 2) + g;
  bool ok = i0 < n;
  int i = ok ? i0 : n - 1;
  int hf = r & 1, er = r >> 1;
  int dg = deg[i];
  const int* cp = csr + row_start[i];
  const f16* sb = HS + (size_t)s * ss + (size_t)hf * 8;
  f16x8 a0 = (f16x8)0, a1 = (f16x8)0;
  if (dg > 0) {
    int dgm = dg - 1;
    // csr prefetch pipeline: indices for the NEXT pair of 8-edge slabs are
    // issued before the current HS loads, breaking the idx->row serial chain.
    int iA = cp[min(er, dgm)];
    int iB = cp[min(er + 8, dgm)];
    for (int u = 0; u < dg; u += 16) {
      int cA = iA, cB = iB;
      iA = cp[min(u + 16 + er, dgm)];
      iB = cp[min(u + 24 + er, dgm)];
      if (u + er < dg)
        a0 += *(const f16x8*)(sb + ((size_t)(unsigned)cA << 4));
      if (u + 8 + er < dg)
        a1 += *(const f16x8*)(sb + ((size_t)(unsigned)cB << 4));
    }
  }
  // reduce 8 edge-slots within the 16-lane group (3 levels, stays in-group)
  f16x8 tv = a0 + a1;
  tv += shfl_xor_f16x8(tv, 2);
  tv += shfl_xor_f16x8(tv, 4);
  tv += shfl_xor_f16x8(tv, 8);
  // epilogue: self-loop + isd + bias + relu
  f16x8 sv = *(const f16x8*)(HS + (size_t)s * ss + (size_t)i * 16 + hf * 8);
  float di = isd[i];
  const float* bp = bias + s * 16 + hf * 8;
  float4 b0 = *(const float4*)bp;
  float4 b1 = *(const float4*)(bp + 4);
  float bv[8] = {b0.x, b0.y, b0.z, b0.w, b1.x, b1.y, b1.z, b1.w};
  f16x8 ov;
#pragma unroll
  for (int j = 0; j < 8; ++j) {
    float v = di * ((float)tv[j] + (float)sv[j]) + bv[j];
    v = v > 0.f ? v : 0.f;
    ov[j] = (f16)v;
  }
  if (ok && r < 2)
    *(f16x8*)(G + (size_t)s * ss + (size_t)i * 16 + hf * 8) = ov;
}

// ---- classifier: out = H_blk @ Wl + bl (fp32 out), 4 nodes/block ----
__global__ __launch_bounds__(256) void k_cls(const f16* __restrict__ H,
                                             const float* __restrict__ Wl,
                                             const float* __restrict__ bl,
                                             float* __restrict__ out, int n) {
  const size_t ss = (size_t)n * 16;
  int wv = threadIdx.x >> 6;
  int ir = (blockIdx.x << 2) + wv;
  int i = ir < n ? ir : n - 1;  // clamp so all waves reach the barrier
  int lane = threadIdx.x & 63;
  __shared__ float tt[4][D];
  if (lane < 16) {
    int s = lane >> 1, hf = lane & 1;
    f16x8 v = *(const f16x8*)(H + (size_t)s * ss + (size_t)i * 16 + hf * 8);
    float* dp = &tt[wv][s * 16 + hf * 8];
#pragma unroll
    for (int j = 0; j < 8; ++j) dp[j] = (float)v[j];
  }
  __syncthreads();
  if (ir < n && lane < N_CLS) {
    float o = bl[lane];
#pragma unroll 4
    for (int k = 0; k < D; k += 4) {
      float4 t4 = *(const float4*)&tt[wv][k];
      o += t4.x * Wl[(k + 0) * N_CLS + lane];
      o += t4.y * Wl[(k + 1) * N_CLS + lane];
      o += t4.z * Wl[(k + 2) * N_CLS + lane];
      o += t4.w * Wl[(k + 3) * N_CLS + lane];
    }
    out[(size_t)ir * N_CLS + lane] = o;
  }
}

extern "C" void kernel_launch(void* const* d_in, const int* in_sizes, int n_in,
                              void* d_out, int out_size, void* d_ws, size_t ws_size,
                              hipStream_t stream) {
  const float* x  = (const float*)d_in[0];
  const int*   ei = (const int*)d_in[1];
  const float* W1 = (const float*)d_in[2];
  const float* b1 = (const float*)d_in[3];
  const float* W2 = (const float*)d_in[4];
  const float* b2 = (const float*)d_in[5];
  const float* Wl = (const float*)d_in[6];
  const float* bl = (const float*)d_in[7];
  float* out = (float*)d_out;

  const int n = in_sizes[0] / D;  // 100000
  const int e = in_sizes[1] / 2;  // 3200000
  const int* src = ei;
  const int* dst = ei + e;
  const int nb = (n + BN - 1) / BN;  // 782

  char* ws = (char*)d_ws;
  size_t off = 0;
  auto alloc = [&](size_t bytes) -> void* {
    void* p = ws + off;
    off += (bytes + 255) & ~(size_t)255;
    return p;
  };
  int*   bcnt      = (int*)alloc(NBMAX * 4);
  int*   bbase     = (int*)alloc(NBMAX * 4);
  int*   bcur      = (int*)alloc(NBMAX * 4);
  int*   deg       = (int*)alloc((size_t)n * 4);
  int*   row_start = (int*)alloc((size_t)n * 4);
  float* isd       = (float*)alloc((size_t)n * 4);
  int*   csr       = (int*)alloc((size_t)e * 4);
  f16*   hA        = (f16*)alloc((size_t)n * D * 2);
  f16*   hB        = (f16*)alloc((size_t)n * D * 2);
  unsigned int* binned = (unsigned int*)hA;  // dead before gemm1 writes hA

  hipMemsetAsync(bcnt, 0, NBMAX * 4, stream);

  const int nwg_place = 512;
  k_hist<<<1024, 256, 0, stream>>>(dst, bcnt, e);
  k_bscan<<<1, 1024, 0, stream>>>(bcnt, bbase, bcur);
  k_place<<<nwg_place, 256, 0, stream>>>(src, dst, bcur, binned, e, nwg_place);
  k_csr<<<nb, 256, 0, stream>>>(binned, bbase, csr, deg, isd, row_start, n);

  int gblocks = (n + 63) / 64;
  int ablocks = ((n + 15) / 16) * 8;  // node-groups x 8 slices (grid % 8 == 0)
  // layer 1
  k_gemm_t<false><<<gblocks, 256, 0, stream>>>(x, W1, isd, hA, n);
  k_aggs<<<ablocks, 256, 0, stream>>>(hA, csr, row_start, deg, isd, b1, hB, n);
  // layer 2
  k_gemm_t<true><<<gblocks, 256, 0, stream>>>(hB, W2, isd, hA, n);
  k_aggs<<<ablocks, 256, 0, stream>>>(hA, csr, row_start, deg, isd, b2, hB, n);
  // classifier
  k_cls<<<(n + 3) / 4, 256, 0, stream>>>(hB, Wl, bl, out, n);
}